// Round 3
// baseline (688.531 us; speedup 1.0000x reference)
//
#include <hip/hip_runtime.h>
#include <cstdint>

#define BB 64
#define PP 8732
#define CC 81
#define PRB 256                        // priors per block (1 per lane)
#define TPB 256
#define NBX ((PP + PRB - 1) / PRB)     // 35 blocks per batch row
#define NPTAIL (PP - (NBX - 1) * PRB)  // 28
#define RREP 16
#define HSTR 257

// ---------- wave (64-lane) reductions ----------
__device__ __forceinline__ float wsum(float v) {
#pragma unroll
  for (int o = 32; o > 0; o >>= 1) v += __shfl_xor(v, o, 64);
  return v;
}
__device__ __forceinline__ int wsumi(int v) {
#pragma unroll
  for (int o = 32; o > 0; o >>= 1) v += __shfl_xor(v, o, 64);
  return v;
}
__device__ __forceinline__ float hub(float d) {
  const float ad = fabsf(d);
  return (ad < 1.f) ? 0.5f * d * d : ad - 0.5f;
}

// zero the poisoned counters (row_done[0..63] + fin_cnt at [64])
__global__ void k_init(int* __restrict__ row_done) {
  const int t = threadIdx.x;
  if (t <= BB) row_done[t] = 0;
}

// ---------- fused kernel ----------
// Streaming phase: 4-lane group owns 4 consecutive priors (324 floats =
// 1296 B, 16B-aligned; single 324 B rows are NOT — this grouping is what
// makes float4 streaming legal). Lane q reads float4s f=q+4t, t=0..19;
// q==0 also reads f=80. Class->prior boundary (81, odd) folds to static
// accumulator indices after unroll; ~12 elements/lane need a predicated
// 2-way select. No LDS, no barriers in the hot path -> 8 blocks/CU.
// Tail phase: last-finishing block per row (row_done atomic) runs the
// radix top-K reading negp from global; last of the 64 finishers
// (fin_cnt atomic) does the 64-row finalize.
__global__ __launch_bounds__(TPB) void k_fused(
    const float* __restrict__ conf, const float* __restrict__ ploc,
    const int* __restrict__ label, const float* __restrict__ gloc,
    float* __restrict__ negp, int* __restrict__ part_cnt,
    float* __restrict__ part_nll, float* __restrict__ part_loc,
    int* __restrict__ row_npos, float* __restrict__ row_nll,
    float* __restrict__ row_loc, float* __restrict__ row_topk,
    int* __restrict__ row_done, float* __restrict__ out) {
  __shared__ int s_hist[RREP * HSTR];   // 16448 B (finisher only)
  __shared__ int s_tot[256];
  __shared__ float sh_n[4], sh_l[4];
  __shared__ int sh_c[4];
  __shared__ uint32_t s_pref;
  __shared__ int s_kk, s_npos, s_flag, s_last;
  __shared__ float s_redf[4];

  int* fin_cnt = row_done + BB;

  const int b = blockIdx.y, bx = blockIdx.x;
  const int tid = threadIdx.x, lane = tid & 63, wave = tid >> 6;
  const int q = tid & 3;
  const int np = (bx == NBX - 1) ? NPTAIL : PRB;   // 256 or 28, both %4==0
  const size_t rowbase = (size_t)b * PP + (size_t)bx * PRB;
  const bool gact = tid < np;                      // group-uniform (np%4==0)

  float nll_acc = 0.f, loc_acc = 0.f;
  int cnt = 0;

  if (gact) {
    const float* chunk = conf + (rowbase + (size_t)(tid & ~3)) * CC;  // 16B-al.
    float a[4] = {0.f, 0.f, 0.f, 0.f};     // exp-sum partials, priors 0..3
    float x0v[4] = {0.f, 0.f, 0.f, 0.f};   // class-0 logits (q==0 owns all)

    auto eat = [&](int C, float x) {       // C = class-linear idx for q==0
      const float ex = __expf(x);
      const int m = C % 81;                // folds after unroll
      if (m <= 68) {
        a[C / 81] += ex;                   // static index for all q
      } else {
        const int qt = (81 - m + 3) >> 2;  // crossing threshold, folds
        if (q >= qt) a[C / 81 + 1] += ex; else a[C / 81] += ex;
      }
      if (m == 0) { if (q == 0) x0v[C / 81] = x; }  // C in {0,81,162,243}
    };
#pragma unroll
    for (int t = 0; t < 20; ++t) {
      const float4 v = *(const float4*)(chunk + 4 * (q + 4 * t));
      eat(16 * t + 0, v.x); eat(16 * t + 1, v.y);
      eat(16 * t + 2, v.z); eat(16 * t + 3, v.w);
    }
    if (q == 0) {                          // f=80: floats 320..323, prior 3
      const float4 v = *(const float4*)(chunk + 320);
      a[3] += __expf(v.x) + __expf(v.y) + __expf(v.z) + __expf(v.w);
    }
    // 4-lane butterfly: all lanes end with all 4 group totals
#pragma unroll
    for (int j = 0; j < 4; ++j) {
      a[j] += __shfl_xor(a[j], 1, 64);
      a[j] += __shfl_xor(a[j], 2, 64);
    }

    // per-lane epilogue: own prior
    const size_t pr = rowbase + tid;
    const int lab = label[pr];             // coalesced dword
    const int lab1 = __shfl(lab, (lane & ~3) + 1, 64);
    const int lab2 = __shfl(lab, (lane & ~3) + 2, 64);
    const int lab3 = __shfl(lab, (lane & ~3) + 3, 64);
    if (lab > 0) {
      const float4 pv = *(const float4*)(ploc + pr * 4);   // 16B-aligned
      const float4 gv = *(const float4*)(gloc + pr * 4);
      loc_acc = hub(pv.x - gv.x) + hub(pv.y - gv.y) +
                hub(pv.z - gv.z) + hub(pv.w - gv.w);
    }
    if (q == 0) {                          // group's negp as one float4 store
      const float l0 = __logf(a[0]), l1 = __logf(a[1]);
      const float l2 = __logf(a[2]), l3 = __logf(a[3]);
      float4 npv;
      npv.x = (lab  > 0) ? 0.f : fmaxf(l0 - x0v[0], 0.f);
      npv.y = (lab1 > 0) ? 0.f : fmaxf(l1 - x0v[1], 0.f);
      npv.z = (lab2 > 0) ? 0.f : fmaxf(l2 - x0v[2], 0.f);
      npv.w = (lab3 > 0) ? 0.f : fmaxf(l3 - x0v[3], 0.f);
      *(float4*)(negp + pr) = npv;         // pr%4==0 here -> 16B-aligned
      if (lab  > 0) { ++cnt; nll_acc += l0 - conf[(pr + 0) * CC + lab ]; }
      if (lab1 > 0) { ++cnt; nll_acc += l1 - conf[(pr + 1) * CC + lab1]; }
      if (lab2 > 0) { ++cnt; nll_acc += l2 - conf[(pr + 2) * CC + lab2]; }
      if (lab3 > 0) { ++cnt; nll_acc += l3 - conf[(pr + 3) * CC + lab3]; }
    }
  }

  // ---- block reduce -> one partial store per block ----
  {
    const float na = wsum(nll_acc);
    const float la = wsum(loc_acc);
    const int ca = wsumi(cnt);
    if (lane == 0) { sh_n[wave] = na; sh_l[wave] = la; sh_c[wave] = ca; }
  }
  __syncthreads();
  if (tid == 0) {
    float tn = 0.f, tl = 0.f; int tc = 0;
#pragma unroll
    for (int w = 0; w < 4; ++w) { tn += sh_n[w]; tl += sh_l[w]; tc += sh_c[w]; }
    const int slot = b * NBX + bx;
    part_cnt[slot] = tc; part_nll[slot] = tn; part_loc[slot] = tl;
  }
  __syncthreads();
  __threadfence();       // release: every wave makes its own stores visible
  __syncthreads();
  if (tid == 0) s_flag = (atomicAdd(&row_done[b], 1) == NBX - 1) ? 1 : 0;
  __syncthreads();
  if (!s_flag) return;   // non-finisher blocks exit; finisher has all 256

  // ================= row finisher: reduce partials + top-K =================
  __threadfence();       // acquire: other blocks' negp/part stores
  if (wave == 0) {
    int c = 0; float n = 0.f, l = 0.f;
    if (lane < NBX) {
      const int slot = b * NBX + lane;
      c = part_cnt[slot]; n = part_nll[slot]; l = part_loc[slot];
    }
    c = wsumi(c); n = wsum(n); l = wsum(l);
    if (lane == 0) { row_npos[b] = c; row_nll[b] = n; row_loc[b] = l; s_npos = c; }
  }
  for (int i = tid; i < RREP * HSTR; i += TPB) s_hist[i] = 0;
  __syncthreads();

  const int npos = s_npos;
  int K = 3 * npos;
  const int mx = PP - npos;
  if (K > mx) K = mx;
  const float* vrow = negp + (size_t)b * PP;

  if (K > 0) {                            // block-uniform branch
    if (tid == 0) { s_pref = 0u; s_kk = K; }
    __syncthreads();
    const int rep = tid & (RREP - 1);

    for (int pass = 0; pass < 4; ++pass) {
      const int sh = 24 - 8 * pass;
      const uint32_t himask = (pass == 0) ? 0u : (0xFFFFFFFFu << (sh + 8));
      const uint32_t pref = s_pref;
      for (int i = tid; i < PP; i += TPB) {
        const uint32_t u = __float_as_uint(vrow[i]);
        if ((u & himask) == (pref & himask))
          atomicAdd(&s_hist[rep * HSTR + ((u >> sh) & 0xFF)], 1);
      }
      __syncthreads();
      {
        int tt = 0;
#pragma unroll
        for (int r = 0; r < RREP; ++r) tt += s_hist[r * HSTR + tid];
        s_tot[tid] = tt;
      }
      __syncthreads();
      for (int i = tid; i < RREP * HSTR; i += TPB) s_hist[i] = 0;
      // wave-0 suffix-scan: find bin with S(bin) >= kk > S(bin+1)
      if (tid < 64) {
        const int l = tid;
        const int e0 = s_tot[4 * l], e1 = s_tot[4 * l + 1];
        const int e2 = s_tot[4 * l + 2], e3 = s_tot[4 * l + 3];
        const int L = e0 + e1 + e2 + e3;
        int x = L;
#pragma unroll
        for (int o = 1; o < 64; o <<= 1) {
          const int v = __shfl_down(x, o, 64);
          if (l + o < 64) x += v;
        }
        const int T = x - L;
        const int S3 = e3 + T, S2 = e2 + S3, S1 = e1 + S2, S0 = e0 + S1;
        const int kk = s_kk;
        const uint32_t pf = s_pref;
        if (S0 >= kk && S1 < kk) { s_pref = pf | ((uint32_t)(4 * l + 0) << sh); s_kk = kk - S1; }
        if (S1 >= kk && S2 < kk) { s_pref = pf | ((uint32_t)(4 * l + 1) << sh); s_kk = kk - S2; }
        if (S2 >= kk && S3 < kk) { s_pref = pf | ((uint32_t)(4 * l + 2) << sh); s_kk = kk - S3; }
        if (S3 >= kk && T  < kk) { s_pref = pf | ((uint32_t)(4 * l + 3) << sh); s_kk = kk - T; }
      }
      __syncthreads();
    }

    const uint32_t T = s_pref;
    const int kk = s_kk;
    float local = 0.f;
    for (int i = tid; i < PP; i += TPB) {
      const uint32_t u = __float_as_uint(vrow[i]);
      if (u > T) local += __uint_as_float(u);
    }
    local = wsum(local);
    if (lane == 0) s_redf[wave] = local;
    __syncthreads();
    if (tid == 0) {
      float tot = 0.f;
#pragma unroll
      for (int w = 0; w < 4; ++w) tot += s_redf[w];
      row_topk[b] = tot + (float)kk * __uint_as_float(T);
    }
  } else {
    if (tid == 0) row_topk[b] = 0.f;
  }

  // ---- last of the 64 finishers does the 64-row finalize ----
  if (tid == 0) {
    __threadfence();     // release row_* (all written by this tid)
    s_last = (atomicAdd(fin_cnt, 1) == BB - 1) ? 1 : 0;
  }
  __syncthreads();
  if (s_last && tid < 64) {
    __threadfence();     // acquire other finishers' row_*
    const int np_ = row_npos[tid];
    const float nllv = row_nll[tid] + row_topk[tid];
    const float locv = row_loc[tid];
    int Kq = 3 * np_;
    const int mxq = PP - np_;
    if (Kq > mxq) Kq = mxq;
    const float nsel = (float)(np_ + Kq);

    const float tot_nll = wsum(nllv);
    const float tot_loc = wsum(locv);
    const float tot_pos = wsum((float)np_);
    const float tot_sel = wsum(nsel);

    const float ce = tot_nll / fmaxf(tot_sel, 1.0f);
    out[tid] = ce / (float)np_;                              // conf_loss (B,1)
    if (tid == 0) out[BB] = tot_loc / fmaxf(tot_pos, 1.0f);  // loc_huber_loss
  }
}

extern "C" void kernel_launch(void* const* d_in, const int* in_sizes, int n_in,
                              void* d_out, int out_size, void* d_ws, size_t ws_size,
                              hipStream_t stream) {
  const float* conf = (const float*)d_in[0];
  const float* ploc = (const float*)d_in[1];
  const int* label = (const int*)d_in[2];
  const float* gloc = (const float*)d_in[3];
  float* out = (float*)d_out;

  float* negp = (float*)d_ws;                          // BB*PP floats
  int* part_cnt = (int*)(negp + (size_t)BB * PP);      // BB*NBX ints
  float* part_nll = (float*)(part_cnt + BB * NBX);     // BB*NBX floats
  float* part_loc = part_nll + BB * NBX;               // BB*NBX floats
  int* row_npos = (int*)(part_loc + BB * NBX);         // BB ints
  float* row_nll = (float*)(row_npos + BB);            // BB floats
  float* row_loc = row_nll + BB;                       // BB floats
  float* row_topk = row_loc + BB;                      // BB floats
  int* row_done = (int*)(row_topk + BB);               // BB + 1 ints (fin_cnt)

  hipLaunchKernelGGL(k_init, dim3(1), dim3(128), 0, stream, row_done);
  hipLaunchKernelGGL(k_fused, dim3(NBX, BB), dim3(TPB), 0, stream,
                     conf, ploc, label, gloc, negp, part_cnt, part_nll, part_loc,
                     row_npos, row_nll, row_loc, row_topk, row_done, out);
}

// Round 4
// 278.209 us; speedup vs baseline: 2.4749x; 2.4749x over previous
//
#include <hip/hip_runtime.h>
#include <cstdint>

#define BB 64
#define PP 8732
#define CC 81
#define PRB 256                        // priors per block (1 per lane)
#define TPB 256
#define NBX ((PP + PRB - 1) / PRB)     // 35 blocks per batch row
#define NPTAIL (PP - (NBX - 1) * PRB)  // 28

#define GLOBAL_AS __attribute__((address_space(1)))
#define LDS_AS __attribute__((address_space(3)))

// ---------- wave (64-lane) reductions ----------
__device__ __forceinline__ float wsum(float v) {
#pragma unroll
  for (int o = 32; o > 0; o >>= 1) v += __shfl_xor(v, o, 64);
  return v;
}
__device__ __forceinline__ int wsumi(int v) {
#pragma unroll
  for (int o = 32; o > 0; o >>= 1) v += __shfl_xor(v, o, 64);
  return v;
}
__device__ __forceinline__ float hub(float d) {
  const float ad = fabsf(d);
  return (ad < 1.f) ? 0.5f * d * d : ad - 0.5f;
}

// ---------- kernel 1: streaming log-softmax stats, float4 direct ----------
// 4-lane group owns 4 consecutive priors (324 floats = 1296 B, 16B-aligned;
// single 324 B rows are NOT -> grouping makes float4 streaming legal).
// Lane q reads float4s f=q+4t, t=0..19; q==0 also reads f=80. Class->prior
// boundary (81, odd) folds to static accumulator indices after unroll.
// No LDS/barriers in the hot path; NO fences/atomics anywhere — the kernel
// boundary is the device-wide release (round-3 lesson: wave-wide
// __threadfence = L2 writeback storm, 520 us with all pipes idle).
__global__ __launch_bounds__(TPB) void k_stream(
    const float* __restrict__ conf, const float* __restrict__ ploc,
    const int* __restrict__ label, const float* __restrict__ gloc,
    float* __restrict__ negp, int* __restrict__ part_cnt,
    float* __restrict__ part_nll, float* __restrict__ part_loc,
    int* __restrict__ fin_cnt) {
  __shared__ float sh_n[4], sh_l[4];
  __shared__ int sh_c[4];

  const int b = blockIdx.y, bx = blockIdx.x;
  const int tid = threadIdx.x, lane = tid & 63, wave = tid >> 6;
  const int q = tid & 3;
  const int np = (bx == NBX - 1) ? NPTAIL : PRB;   // 256 or 28, both %4==0
  const size_t rowbase = (size_t)b * PP + (size_t)bx * PRB;
  const bool gact = tid < np;                      // group-uniform (np%4==0)

  if (bx == 0 && b == 0 && tid == 0) *fin_cnt = 0; // stream-ordered vs k_topk

  float nll_acc = 0.f, loc_acc = 0.f;
  int cnt = 0;

  if (gact) {
    const float* chunk = conf + (rowbase + (size_t)(tid & ~3)) * CC;  // 16B-al.
    float a[4] = {0.f, 0.f, 0.f, 0.f};     // exp-sum partials, priors 0..3
    float x0v[4] = {0.f, 0.f, 0.f, 0.f};   // class-0 logits (q==0 owns all)

    auto eat = [&](int C, float x) {       // C = class-linear idx for q==0
      const float ex = __expf(x);
      const int m = C % 81;                // folds after unroll
      if (m <= 68) {
        a[C / 81] += ex;                   // static index for all q
      } else {
        const int qt = (81 - m + 3) >> 2;  // crossing threshold, folds
        if (q >= qt) a[C / 81 + 1] += ex; else a[C / 81] += ex;
      }
      if (m == 0) { if (q == 0) x0v[C / 81] = x; }  // C in {0,81,162,243}
    };
#pragma unroll
    for (int t = 0; t < 20; ++t) {
      const float4 v = *(const float4*)(chunk + 4 * (q + 4 * t));
      eat(16 * t + 0, v.x); eat(16 * t + 1, v.y);
      eat(16 * t + 2, v.z); eat(16 * t + 3, v.w);
    }
    if (q == 0) {                          // f=80: floats 320..323, prior 3
      const float4 v = *(const float4*)(chunk + 320);
      a[3] += __expf(v.x) + __expf(v.y) + __expf(v.z) + __expf(v.w);
    }
    // 4-lane butterfly: all lanes end with all 4 group totals
#pragma unroll
    for (int j = 0; j < 4; ++j) {
      a[j] += __shfl_xor(a[j], 1, 64);
      a[j] += __shfl_xor(a[j], 2, 64);
    }

    // per-lane epilogue: own prior
    const size_t pr = rowbase + tid;
    const int lab = label[pr];             // coalesced dword
    const int lab1 = __shfl(lab, (lane & ~3) + 1, 64);
    const int lab2 = __shfl(lab, (lane & ~3) + 2, 64);
    const int lab3 = __shfl(lab, (lane & ~3) + 3, 64);
    if (lab > 0) {
      const float4 pv = *(const float4*)(ploc + pr * 4);   // 16B-aligned
      const float4 gv = *(const float4*)(gloc + pr * 4);
      loc_acc = hub(pv.x - gv.x) + hub(pv.y - gv.y) +
                hub(pv.z - gv.z) + hub(pv.w - gv.w);
    }
    if (q == 0) {                          // group's negp as one float4 store
      const float l0 = __logf(a[0]), l1 = __logf(a[1]);
      const float l2 = __logf(a[2]), l3 = __logf(a[3]);
      float4 npv;
      npv.x = (lab  > 0) ? 0.f : fmaxf(l0 - x0v[0], 0.f);
      npv.y = (lab1 > 0) ? 0.f : fmaxf(l1 - x0v[1], 0.f);
      npv.z = (lab2 > 0) ? 0.f : fmaxf(l2 - x0v[2], 0.f);
      npv.w = (lab3 > 0) ? 0.f : fmaxf(l3 - x0v[3], 0.f);
      *(float4*)(negp + pr) = npv;         // pr%4==0 -> 16B-aligned
      if (lab  > 0) { ++cnt; nll_acc += l0 - conf[(pr + 0) * CC + lab ]; }
      if (lab1 > 0) { ++cnt; nll_acc += l1 - conf[(pr + 1) * CC + lab1]; }
      if (lab2 > 0) { ++cnt; nll_acc += l2 - conf[(pr + 2) * CC + lab2]; }
      if (lab3 > 0) { ++cnt; nll_acc += l3 - conf[(pr + 3) * CC + lab3]; }
    }
  }

  // ---- block reduce -> one plain store per block (no atomics, no fences) ----
  {
    const float na = wsum(nll_acc);
    const float la = wsum(loc_acc);
    const int ca = wsumi(cnt);
    if (lane == 0) { sh_n[wave] = na; sh_l[wave] = la; sh_c[wave] = ca; }
  }
  __syncthreads();
  if (tid == 0) {
    float tn = 0.f, tl = 0.f; int tc = 0;
#pragma unroll
    for (int w = 0; w < 4; ++w) { tn += sh_n[w]; tl += sh_l[w]; tc += sh_c[w]; }
    const int slot = b * NBX + bx;
    part_cnt[slot] = tc; part_nll[slot] = tn; part_loc[slot] = tl;
  }
}

// ---------- kernel 2: per-row top-K radix select + fused finalize ----------
// Round-2-proven structure: 64 blocks x 1024 threads, DMA-stage the row,
// radix select, finalize by the LAST block (tid-0-only fences: 64 total).
#define RREP 16
#define HSTR 257
#define TTK 1024
__global__ __launch_bounds__(TTK) void k_topk(
    const float* __restrict__ negp, const int* __restrict__ part_cnt,
    const float* __restrict__ part_nll, const float* __restrict__ part_loc,
    int* __restrict__ row_npos, float* __restrict__ row_nll,
    float* __restrict__ row_loc, float* __restrict__ row_topk,
    int* __restrict__ fin_cnt, float* __restrict__ out) {
  __shared__ uint32_t s_v[PP];            // 34928 B
  __shared__ int s_hist[RREP * HSTR];     // 16448 B
  __shared__ int s_tot[256];
  __shared__ uint32_t s_pref;
  __shared__ int s_kk;
  __shared__ int s_npos;
  __shared__ int s_last;
  __shared__ float s_redf[TTK / 64];

  const int b = blockIdx.x;
  const int tid = threadIdx.x;
  const int lane = tid & 63, wave = tid >> 6;

  // ---- async DMA stage of the 8732 values (PP = 2183*4, base 16B-aligned)
  {
    const GLOBAL_AS float* g = (const GLOBAL_AS float*)(negp + (size_t)b * PP);
    LDS_AS uint32_t* l = (LDS_AS uint32_t*)s_v;
    for (int i = tid; i < PP / 4; i += TTK)
      __builtin_amdgcn_global_load_lds((const GLOBAL_AS void*)(g + 4 * i),
                                       (LDS_AS void*)(l + 4 * i), 16, 0, 0);
  }

  // ---- overlap: reduce this row's 35 partials + clear pass-0 histogram ----
  if (wave == 0) {
    int c = 0; float n = 0.f, l = 0.f;
    if (lane < NBX) {
      const int slot = b * NBX + lane;
      c = part_cnt[slot]; n = part_nll[slot]; l = part_loc[slot];
    }
    c = wsumi(c); n = wsum(n); l = wsum(l);
    if (lane == 0) { row_npos[b] = c; row_nll[b] = n; row_loc[b] = l; s_npos = c; }
  }
  for (int i = tid; i < RREP * HSTR; i += TTK) s_hist[i] = 0;
  __syncthreads();                        // drains DMA + publishes s_npos

  const int npos = s_npos;
  int K = 3 * npos;
  const int mx = PP - npos;
  if (K > mx) K = mx;

  if (K > 0) {                            // block-uniform branch
    if (tid == 0) { s_pref = 0u; s_kk = K; }
    __syncthreads();
    const int rep = tid & (RREP - 1);

    for (int pass = 0; pass < 4; ++pass) {
      const int sh = 24 - 8 * pass;
      const uint32_t himask = (pass == 0) ? 0u : (0xFFFFFFFFu << (sh + 8));
      const uint32_t pref = s_pref;
      for (int i = tid; i < PP; i += TTK) {
        const uint32_t u = s_v[i];
        if ((u & himask) == (pref & himask))
          atomicAdd(&s_hist[rep * HSTR + ((u >> sh) & 0xFF)], 1);
      }
      __syncthreads();
      if (tid < 256) {
        int tt = 0;
#pragma unroll
        for (int rr = 0; rr < RREP; ++rr) tt += s_hist[rr * HSTR + tid];
        s_tot[tid] = tt;
      }
      __syncthreads();
      for (int i = tid; i < RREP * HSTR; i += TTK) s_hist[i] = 0;
      // wave-0 suffix-scan: find bin with S(bin) >= kk > S(bin+1)
      if (tid < 64) {
        const int l = tid;
        const int e0 = s_tot[4 * l], e1 = s_tot[4 * l + 1];
        const int e2 = s_tot[4 * l + 2], e3 = s_tot[4 * l + 3];
        const int L = e0 + e1 + e2 + e3;
        int x = L;
#pragma unroll
        for (int o = 1; o < 64; o <<= 1) {
          const int v = __shfl_down(x, o, 64);
          if (l + o < 64) x += v;
        }
        const int T = x - L;
        const int S3 = e3 + T, S2 = e2 + S3, S1 = e1 + S2, S0 = e0 + S1;
        const int kk = s_kk;
        const uint32_t pf = s_pref;
        if (S0 >= kk && S1 < kk) { s_pref = pf | ((uint32_t)(4 * l + 0) << sh); s_kk = kk - S1; }
        if (S1 >= kk && S2 < kk) { s_pref = pf | ((uint32_t)(4 * l + 1) << sh); s_kk = kk - S2; }
        if (S2 >= kk && S3 < kk) { s_pref = pf | ((uint32_t)(4 * l + 2) << sh); s_kk = kk - S3; }
        if (S3 >= kk && T  < kk) { s_pref = pf | ((uint32_t)(4 * l + 3) << sh); s_kk = kk - T; }
      }
      __syncthreads();
    }

    const uint32_t T = s_pref;
    const int kk = s_kk;
    float local = 0.f;
    for (int i = tid; i < PP; i += TTK) {
      const uint32_t u = s_v[i];
      if (u > T) local += __uint_as_float(u);
    }
    local = wsum(local);
    if (lane == 0) s_redf[wave] = local;
    __syncthreads();
    if (tid == 0) {
      float tot = 0.f;
#pragma unroll
      for (int w = 0; w < TTK / 64; ++w) tot += s_redf[w];
      row_topk[b] = tot + (float)kk * __uint_as_float(T);
    }
  } else {
    if (tid == 0) row_topk[b] = 0.f;
  }

  // ---- fused finalize: last block reduces all 64 rows (tid-0-only fences) ----
  if (tid == 0) {
    __threadfence();                      // release row_* (written by tid 0)
    s_last = (atomicAdd(fin_cnt, 1) == BB - 1) ? 1 : 0;
  }
  __syncthreads();
  if (s_last && tid < 64) {
    __threadfence();                      // acquire other blocks' row_*
    const int np_ = row_npos[tid];
    const float nllv = row_nll[tid] + row_topk[tid];
    const float locv = row_loc[tid];
    int Kq = 3 * np_;
    const int mxq = PP - np_;
    if (Kq > mxq) Kq = mxq;
    const float nsel = (float)(np_ + Kq);

    const float tot_nll = wsum(nllv);
    const float tot_loc = wsum(locv);
    const float tot_pos = wsum((float)np_);
    const float tot_sel = wsum(nsel);

    const float ce = tot_nll / fmaxf(tot_sel, 1.0f);
    out[tid] = ce / (float)np_;                              // conf_loss (B,1)
    if (tid == 0) out[BB] = tot_loc / fmaxf(tot_pos, 1.0f);  // loc_huber_loss
  }
}

extern "C" void kernel_launch(void* const* d_in, const int* in_sizes, int n_in,
                              void* d_out, int out_size, void* d_ws, size_t ws_size,
                              hipStream_t stream) {
  const float* conf = (const float*)d_in[0];
  const float* ploc = (const float*)d_in[1];
  const int* label = (const int*)d_in[2];
  const float* gloc = (const float*)d_in[3];
  float* out = (float*)d_out;

  float* negp = (float*)d_ws;                          // BB*PP floats
  int* part_cnt = (int*)(negp + (size_t)BB * PP);      // BB*NBX ints
  float* part_nll = (float*)(part_cnt + BB * NBX);     // BB*NBX floats
  float* part_loc = part_nll + BB * NBX;               // BB*NBX floats
  int* row_npos = (int*)(part_loc + BB * NBX);         // BB ints
  float* row_nll = (float*)(row_npos + BB);            // BB floats
  float* row_loc = row_nll + BB;                       // BB floats
  float* row_topk = row_loc + BB;                      // BB floats
  int* fin_cnt = (int*)(row_topk + BB);                // 1 int

  hipLaunchKernelGGL(k_stream, dim3(NBX, BB), dim3(TPB), 0, stream,
                     conf, ploc, label, gloc, negp, part_cnt, part_nll, part_loc,
                     fin_cnt);
  hipLaunchKernelGGL(k_topk, dim3(BB), dim3(TTK), 0, stream,
                     negp, part_cnt, part_nll, part_loc,
                     row_npos, row_nll, row_loc, row_topk, fin_cnt, out);
}